// Round 6
// baseline (242.200 us; speedup 1.0000x reference)
//
#include <hip/hip_runtime.h>
#include <hip/hip_bf16.h>
#include <math.h>

// Problem constants
#define BB 2
#define SS 2048
#define DD 1024
#define HH 16
#define HD 64

typedef __attribute__((ext_vector_type(8))) _Float16 f16x8;
typedef __attribute__((ext_vector_type(2))) __fp16 fp16x2;
typedef __attribute__((ext_vector_type(8))) unsigned short u16x8;
typedef __attribute__((ext_vector_type(4))) float f32x4;
typedef __attribute__((ext_vector_type(4))) unsigned short u16x4;

__device__ __forceinline__ unsigned short hbits(_Float16 h) {
    union { _Float16 h; unsigned short s; } u; u.h = h; return u.s;
}

// XOR-swizzled 64x64 fp16 tile: off(row, col) = row*64 + ((col>>3 ^ row&7)<<3) + col&7
__device__ __forceinline__ int swz(int row, int grp) {
    return (row << 6) + (((grp) ^ (row & 7)) << 3);
}

__device__ __forceinline__ float fexp2(float x) {
#if __has_builtin(__builtin_amdgcn_exp2f)
    return __builtin_amdgcn_exp2f(x);
#else
    return exp2f(x);
#endif
}

__device__ __forceinline__ u16x4 pack4(float p0, float p1, float p2, float p3) {
#if __has_builtin(__builtin_amdgcn_cvt_pkrtz)
    union { fp16x2 h[2]; u16x4 u; } pu;
    pu.h[0] = __builtin_amdgcn_cvt_pkrtz(p0, p1);
    pu.h[1] = __builtin_amdgcn_cvt_pkrtz(p2, p3);
    return pu.u;
#else
    u16x4 r;
    r[0] = hbits((_Float16)p0); r[1] = hbits((_Float16)p1);
    r[2] = hbits((_Float16)p2); r[3] = hbits((_Float16)p3);
    return r;
#endif
}

// async global->LDS 16B/lane: lds dest = wave-uniform base + lane*16.
__device__ __forceinline__ void gload_lds16(const unsigned short* g, unsigned short* l) {
#if __has_builtin(__builtin_amdgcn_global_load_lds)
    auto gp = (const __attribute__((address_space(1))) unsigned int*)(uintptr_t)g;
    auto lp = (__attribute__((address_space(3))) unsigned int*)(uintptr_t)l;
    __builtin_amdgcn_global_load_lds(gp, lp, 16, 0, 0);
#else
    *(u16x8*)(l + (threadIdx.x & 63) * 8) = *(const u16x8*)g;
#endif
}

// Counted-vmcnt barriers for the (unchanged) out_gemm / attn kernels.
__device__ __forceinline__ void wait4_barrier() {
    asm volatile("s_waitcnt vmcnt(4) lgkmcnt(0)\n\ts_barrier" ::: "memory");
}
__device__ __forceinline__ void wait6_barrier() {
    asm volatile("s_waitcnt vmcnt(6) lgkmcnt(0)\n\ts_barrier" ::: "memory");
}
__device__ __forceinline__ void wait0_barrier() {
    asm volatile("s_waitcnt vmcnt(0) lgkmcnt(0)\n\ts_barrier" ::: "memory");
}

// ---------------------------------------------------------------------------
// Prepass: X -> fp16 (same layout); W -> fp16 transposed rows WT[n][k].
// ---------------------------------------------------------------------------
__global__ __launch_bounds__(256) void prep_convert(
    const float* __restrict__ X,
    const float* __restrict__ Wq, const float* __restrict__ Wk,
    const float* __restrict__ Wv, const float* __restrict__ Wo,
    unsigned short* __restrict__ Xh, unsigned short* __restrict__ WT)
{
    __shared__ __align__(16) unsigned short LT[64 * 68];
    const int bid = blockIdx.x;
    const int tid = threadIdx.x;

    if (bid < 2048) {
        const int base = bid * 2048 + tid * 8;
        float4 a = *(const float4*)&X[base];
        float4 b = *(const float4*)&X[base + 4];
        u16x8 o;
        o[0] = hbits((_Float16)a.x); o[1] = hbits((_Float16)a.y);
        o[2] = hbits((_Float16)a.z); o[3] = hbits((_Float16)a.w);
        o[4] = hbits((_Float16)b.x); o[5] = hbits((_Float16)b.y);
        o[6] = hbits((_Float16)b.z); o[7] = hbits((_Float16)b.w);
        *(u16x8*)&Xh[base] = o;
        return;
    }

    const int t = bid - 2048;
    const float* src;
    size_t stride;
    int outRow0, kcol0;
    if (t < 768) {
        const int nt = t >> 4, ktile = t & 15;
        const int sel = nt >> 4, hh = nt & 15;
        const float* Ws = (sel == 0) ? Wq : ((sel == 1) ? Wk : Wv);
        src = Ws + (size_t)hh * (DD * HD) + (size_t)ktile * 64 * HD;
        stride = HD;
        outRow0 = nt * 64;
        kcol0 = ktile * 64;
    } else {
        const int tt = t - 768;
        const int nt = tt & 15, ktile = tt >> 4;
        src = Wo + (size_t)ktile * 64 * DD + nt * 64;
        stride = DD;
        outRow0 = 3072 + nt * 64;
        kcol0 = ktile * 64;
    }

    const int e = tid & 63, dq = tid >> 6;
#pragma unroll
    for (int p = 0; p < 16; p++) {
        const int dl = p * 4 + dq;
        LT[e * 68 + dl] = hbits((_Float16)src[(size_t)dl * stride + e]);
    }
    __syncthreads();
    const int eo = tid >> 2, d16 = (tid & 3) * 16;
#pragma unroll
    for (int j = 0; j < 4; j++) {
        *(ushort4*)&WT[(size_t)(outRow0 + eo) * DD + kcol0 + d16 + j * 4] =
            *(const ushort4*)&LT[eo * 68 + d16 + j * 4];
    }
}

// ---------------------------------------------------------------------------
// QKV GEMM, BARRIER-FREE: block = 128 rows x ONE head (64 cols) x all of
// Q,K,V. 4 waves; each wave owns a PRIVATE 64x32-per-sel slice with private
// 2-buffer LDS staging, synced only by its own counted vmcnt (never 0 until
// tail). Zero __syncthreads in the K-loop -> no 12-wave barrier convoy.
// A-fragment reuse x3 (Q,K,V share A): 24 MFMA per 10 ds_read per iter.
// LDS 80 KiB -> 2 blocks/CU; grid 512 = 2/CU exact, no tail.
// ---------------------------------------------------------------------------
#define GBM 128
#define GBN 128
#define GBK 64
#define NKT (DD / GBK)   // 16 (out_gemm)
#define QBK 32
#define QNKT (DD / QBK)  // 32 (qkv_gemm)

__global__ __launch_bounds__(256, 2) void qkv_gemm(
    const unsigned short* __restrict__ Xh, const unsigned short* __restrict__ WT,
    const float* __restrict__ bq, const float* __restrict__ bk,
    const float* __restrict__ bv,
    unsigned short* __restrict__ qh, unsigned short* __restrict__ kh,
    unsigned short* __restrict__ vTs, unsigned int* __restrict__ kc2)
{
    // wave-private: AW[wave][buf][4 chunks x 512], BW[wave][sel][buf][2 x 512]
    __shared__ __align__(16) unsigned short AW[4][2][2048];   // 32 KiB
    __shared__ __align__(16) unsigned short BW[4][3][2][1024]; // 48 KiB

    const int tid  = threadIdx.x;
    const int lane = tid & 63;
    const int w    = tid >> 6;
    const int wm   = w & 1, wn = w >> 1;
    const int l15  = lane & 15, quad = lane >> 4;
    const int m0   = blockIdx.y * 128;
    const int head = blockIdx.x;          // n-range = head*64 .. +64

    const unsigned short* Ab = Xh + (size_t)(m0 + wm * 64) * DD;
    const unsigned short* Bb = WT + (size_t)(head * 64 + wn * 32) * DD;

    int aoff[4], boff[2];
#pragma unroll
    for (int c = 0; c < 4; c++) aoff[c] = (c * 16 + l15) * DD + quad * 8;
#pragma unroll
    for (int c = 0; c < 2; c++) boff[c] = (c * 16 + l15) * DD + quad * 8;

    f32x4 acc[3][4][2];
#pragma unroll
    for (int s = 0; s < 3; s++)
#pragma unroll
        for (int i = 0; i < 4; i++)
#pragma unroll
            for (int j = 0; j < 2; j++) acc[s][i][j] = (f32x4){0.f, 0.f, 0.f, 0.f};

    // stage one K-tile (ke = element offset) into wave-private buf b: 10 loads
    auto STAGE = [&](int b, int ke) {
#pragma unroll
        for (int c = 0; c < 4; c++)
            gload_lds16(Ab + aoff[c] + ke, &AW[w][b][c * 512]);
#pragma unroll
        for (int sel = 0; sel < 3; sel++)
#pragma unroll
            for (int c = 0; c < 2; c++)
                gload_lds16(Bb + (size_t)sel * 1024 * DD + boff[c] + ke,
                            &BW[w][sel][b][c * 512]);
    };

    STAGE(0, 0);
    STAGE(1, QBK);
    asm volatile("s_waitcnt vmcnt(10)" ::: "memory");   // buf0 landed

    for (int t = 0; t < QNKT; t++) {
        const int b = t & 1;
        f16x8 af[4], bf[3][2];
#pragma unroll
        for (int ms = 0; ms < 4; ms++)
            af[ms] = *(const f16x8*)&AW[w][b][ms * 512 + lane * 8];
#pragma unroll
        for (int sel = 0; sel < 3; sel++)
#pragma unroll
            for (int ns = 0; ns < 2; ns++)
                bf[sel][ns] = *(const f16x8*)&BW[w][sel][b][ns * 512 + lane * 8];
        // frags now in regs; allow overwrite of buf b by DMA(t+2)
        asm volatile("s_waitcnt lgkmcnt(0)" ::: "memory");
        __builtin_amdgcn_sched_barrier(0);
        if (t + 2 < QNKT) STAGE(b, (t + 2) * QBK);
#pragma unroll
        for (int sel = 0; sel < 3; sel++)
#pragma unroll
            for (int ms = 0; ms < 4; ms++)
#pragma unroll
                for (int ns = 0; ns < 2; ns++)
                    acc[sel][ms][ns] = __builtin_amdgcn_mfma_f32_16x16x32_f16(
                        af[ms], bf[sel][ns], acc[sel][ms][ns], 0, 0, 0);
        // own-wave sync only: t+1's 10 loads done, t+2's 10 stay in flight
        if (t < QNKT - 2)       asm volatile("s_waitcnt vmcnt(10)" ::: "memory");
        else if (t == QNKT - 2) asm volatile("s_waitcnt vmcnt(0)"  ::: "memory");
    }

    // ---- epilogue: bias + fp16 stores; cross-wave kc2 row-norm reduction
    __syncthreads();                       // all waves' loops + DMA complete
    float* rs = (float*)&AW[0][0][0];      // alias 128 floats over AW
    if (tid < 128) rs[tid] = 0.f;
    __syncthreads();

    const int bblk = m0 >> 11;
    const size_t bh_base = ((size_t)bblk * HH + head) * (size_t)SS * HD;

#pragma unroll
    for (int ms = 0; ms < 4; ms++) {
#pragma unroll
        for (int rr = 0; rr < 4; rr++) {
            const int rloc = wm * 64 + ms * 16 + quad * 4 + rr;
            const int s    = (m0 + rloc) & (SS - 1);
            const int s63  = s & 63;
            float v2 = 0.0f;
#pragma unroll
            for (int ns = 0; ns < 2; ns++) {
                const int e = wn * 32 + ns * 16 + l15;
                const float vq = acc[0][ms][ns][rr] + bq[head * HD + e];
                qh[bh_base + (size_t)s * HD + e] = hbits((_Float16)vq);
                const float vk = acc[1][ms][ns][rr] + bk[head * HD + e];
                v2 = fmaf(vk, vk, v2);
                kh[bh_base + (size_t)(s >> 6) * 4096 + swz(s63, e >> 3) + (e & 7)] =
                    hbits((_Float16)vk);
                const float vv = acc[2][ms][ns][rr] + bv[head * HD + e];
                vTs[bh_base + (size_t)(s >> 6) * 4096 + swz(e, s63 >> 3) + (s63 & 7)] =
                    hbits((_Float16)vv);
            }
            v2 += __shfl_xor(v2, 1);
            v2 += __shfl_xor(v2, 2);
            v2 += __shfl_xor(v2, 4);
            v2 += __shfl_xor(v2, 8);
            if (l15 == 0) atomicAdd(&rs[rloc], v2);  // both wn halves sum here
        }
    }
    __syncthreads();
    if (w == 0) {
        float mx = fmaxf(rs[lane], rs[64 + lane]);
        mx = fmaxf(mx, __shfl_xor(mx, 1));
        mx = fmaxf(mx, __shfl_xor(mx, 2));
        mx = fmaxf(mx, __shfl_xor(mx, 4));
        mx = fmaxf(mx, __shfl_xor(mx, 8));
        mx = fmaxf(mx, __shfl_xor(mx, 16));
        mx = fmaxf(mx, __shfl_xor(mx, 32));
        if (lane == 0)
            atomicMax(&kc2[bblk * HH + head], __float_as_uint(mx));
    }
}

// ---------------------------------------------------------------------------
// out GEMM 128x64: grid 512 = 2 blocks/CU exact, 3-buf depth-2 counted
// vmcnt, XCD swizzle (512 = 8 x 64). Unchanged from round 5.
// ---------------------------------------------------------------------------
__global__ __launch_bounds__(256, 2) void out_gemm(
    const unsigned short* __restrict__ Ctxh, const unsigned short* __restrict__ WoT,
    const float* __restrict__ bo, float* __restrict__ out)
{
    __shared__ __align__(16) unsigned short As[3][16 * 512];
    __shared__ __align__(16) unsigned short Bs[3][8 * 512];

    const int tid = threadIdx.x;
    const int f  = blockIdx.y * 16 + blockIdx.x;
    const int fs = (f & 7) * 64 + (f >> 3);
    const int bx = fs % 16, by = fs / 16;
    const int m0 = by * 128;
    const int n0 = bx * 64;
    const int lane = tid & 63;
    const int w = tid >> 6;
    const int wm = w & 1, wn = w >> 1;
    const int l15 = lane & 15, quad = lane >> 4;

    int g_off[4];
#pragma unroll
    for (int p = 0; p < 4; p++) {
        const int c = p * 4 + w;
        g_off[p] = ((c >> 1) * 16 + l15) * DD + (c & 1) * 32 + quad * 8;
    }

    f32x4 acc[4][2];
#pragma unroll
    for (int i = 0; i < 4; i++)
#pragma unroll
        for (int j = 0; j < 2; j++) acc[i][j] = (f32x4){0.f, 0.f, 0.f, 0.f};

    const unsigned short* Abase = Ctxh + (size_t)m0 * DD;
    const unsigned short* Bbase = WoT + (size_t)n0 * DD;

#pragma unroll
    for (int p = 0; p < 4; p++)
        gload_lds16(Abase + g_off[p], &As[0][(p * 4 + w) * 512]);
#pragma unroll
    for (int p = 0; p < 2; p++)
        gload_lds16(Bbase + g_off[p], &Bs[0][(p * 4 + w) * 512]);
#pragma unroll
    for (int p = 0; p < 4; p++)
        gload_lds16(Abase + g_off[p] + GBK, &As[1][(p * 4 + w) * 512]);
#pragma unroll
    for (int p = 0; p < 2; p++)
        gload_lds16(Bbase + g_off[p] + GBK, &Bs[1][(p * 4 + w) * 512]);
    wait0_barrier();

    int cur = 0, pre = 2;
    for (int it = 0; it < NKT; it++) {
        if (it + 2 < NKT) {
            const int kt2 = (it + 2) * GBK;
#pragma unroll
            for (int p = 0; p < 4; p++)
                gload_lds16(Abase + g_off[p] + kt2, &As[pre][(p * 4 + w) * 512]);
#pragma unroll
            for (int p = 0; p < 2; p++)
                gload_lds16(Bbase + g_off[p] + kt2, &Bs[pre][(p * 4 + w) * 512]);
        }
#pragma unroll
        for (int ks = 0; ks < 2; ks++) {
            f16x8 af[4], bf[2];
#pragma unroll
            for (int i = 0; i < 4; i++)
                af[i] = *(const f16x8*)&As[cur][((wm * 4 + i) * 2 + ks) * 512 + lane * 8];
#pragma unroll
            for (int j = 0; j < 2; j++)
                bf[j] = *(const f16x8*)&Bs[cur][((wn * 2 + j) * 2 + ks) * 512 + lane * 8];
#pragma unroll
            for (int ns = 0; ns < 2; ns++)
#pragma unroll
                for (int ms = 0; ms < 4; ms++)
                    acc[ms][ns] = __builtin_amdgcn_mfma_f32_16x16x32_f16(
                        af[ms], bf[ns], acc[ms][ns], 0, 0, 0);
        }
        if (it < NKT - 2)       wait6_barrier();
        else if (it == NKT - 2) wait0_barrier();
        cur = (cur == 2) ? 0 : cur + 1;
        pre = (pre == 2) ? 0 : pre + 1;
    }

#pragma unroll
    for (int ms = 0; ms < 4; ms++) {
#pragma unroll
        for (int rr = 0; rr < 4; rr++) {
            const size_t m = (size_t)(m0 + wm * 64 + ms * 16 + quad * 4 + rr);
#pragma unroll
            for (int ns = 0; ns < 2; ns++) {
                const int n = n0 + wn * 32 + ns * 16 + l15;
                out[m * DD + n] = acc[ms][ns][rr] + bo[n];
            }
        }
    }
}

// ---------------------------------------------------------------------------
// fp16 MFMA flash attention (S^T), fixed-m softmax, triple-buffered counted-
// vmcnt DMA, XCD swizzle, setprio. Unchanged from round 5.
// ---------------------------------------------------------------------------
#define TQB 128
#define TKB 64
#define NT (SS / TKB)    // 32
#define C1 0.1803368801111204f   // 0.125 * log2(e)

__global__ __launch_bounds__(256, 2) void attn_mfma(
    const unsigned short* __restrict__ qh, const unsigned short* __restrict__ kh,
    const unsigned short* __restrict__ vTs, const unsigned int* __restrict__ kc2,
    unsigned short* __restrict__ ctxh)
{
    __shared__ __align__(16) unsigned short KL [3][TKB * 64];
    __shared__ __align__(16) unsigned short VtL[3][HD * 64];
    __shared__ __align__(16) unsigned short PsL[4][32 * 64];

    const int tid  = threadIdx.x;
    const int lane = tid & 63;
    const int w    = tid >> 6;
    const int l15  = lane & 15;
    const int quad = lane >> 4;
    const int f  = blockIdx.y * 16 + blockIdx.x;
    const int fs = (f & 7) * 64 + (f >> 3);
    const int bh = fs >> 4;
    const int q0 = (fs & 15) * TQB;

    const float kfac = sqrtf(__uint_as_float(kc2[bh])) * 1.01f * C1;

    f16x8 qf[2][2];
    float M2[2];
#pragma unroll
    for (int msub = 0; msub < 2; msub++) {
        const unsigned short* qrow =
            qh + ((size_t)bh * SS + q0 + w * 32 + msub * 16 + l15) * HD;
        float nq2 = 0.0f;
#pragma unroll
        for (int dstep = 0; dstep < 2; dstep++) {
            qf[msub][dstep] = *(const f16x8*)&qrow[dstep * 32 + quad * 8];
#pragma unroll
            for (int j = 0; j < 8; j++) {
                const float x = (float)qf[msub][dstep][j];
                nq2 = fmaf(x, x, nq2);
            }
        }
        nq2 += __shfl_xor(nq2, 16);
        nq2 += __shfl_xor(nq2, 32);
        M2[msub] = sqrtf(nq2) * kfac;
    }

    f16x8 ones;
#pragma unroll
    for (int j = 0; j < 8; j++) ones[j] = (_Float16)1.0f;

    f32x4 o[2][4], lones[2];
#pragma unroll
    for (int ms = 0; ms < 2; ms++) {
        lones[ms] = (f32x4){0.f, 0.f, 0.f, 0.f};
#pragma unroll
        for (int e = 0; e < 4; e++) o[ms][e] = (f32x4){0.f, 0.f, 0.f, 0.f};
    }

    const unsigned short* kb0 = kh  + (size_t)bh * SS * HD;
    const unsigned short* vb0 = vTs + (size_t)bh * SS * HD;

    gload_lds16(kb0 + tid * 8,        &KL [0][w * 512]);
    gload_lds16(kb0 + 2048 + tid * 8, &KL [0][2048 + w * 512]);
    gload_lds16(vb0 + tid * 8,        &VtL[0][w * 512]);
    gload_lds16(vb0 + 2048 + tid * 8, &VtL[0][2048 + w * 512]);
    gload_lds16(kb0 + 4096 + tid * 8, &KL [1][w * 512]);
    gload_lds16(kb0 + 6144 + tid * 8, &KL [1][2048 + w * 512]);
    gload_lds16(vb0 + 4096 + tid * 8, &VtL[1][w * 512]);
    gload_lds16(vb0 + 6144 + tid * 8, &VtL[1][2048 + w * 512]);
    wait0_barrier();

    int cur = 0, pre = 2;
    for (int t = 0; t < NT; t++) {
        if (t + 2 < NT) {
            const unsigned short* kb = kb0 + (size_t)(t + 2) * 4096;
            const unsigned short* vb = vb0 + (size_t)(t + 2) * 4096;
            gload_lds16(kb + tid * 8,        &KL [pre][w * 512]);
            gload_lds16(kb + 2048 + tid * 8, &KL [pre][2048 + w * 512]);
            gload_lds16(vb + tid * 8,        &VtL[pre][w * 512]);
            gload_lds16(vb + 2048 + tid * 8, &VtL[pre][2048 + w * 512]);
        }

        f32x4 sc[2][4];
        __builtin_amdgcn_s_setprio(1);
#pragma unroll
        for (int ksub = 0; ksub < 4; ksub++) {
            const int row = ksub * 16 + l15;
            f16x8 k0 = *(const f16x8*)&KL[cur][swz(row, quad)];
            f16x8 k1 = *(const f16x8*)&KL[cur][swz(row, 4 + quad)];
#pragma unroll
            for (int msub = 0; msub < 2; msub++) {
                f32x4 a = (f32x4){0.f, 0.f, 0.f, 0.f};
                a = __builtin_amdgcn_mfma_f32_16x16x32_f16(k0, qf[msub][0], a, 0, 0, 0);
                a = __builtin_amdgcn_mfma_f32_16x16x32_f16(k1, qf[msub][1], a, 0, 0, 0);
                sc[msub][ksub] = a;
            }
        }
        __builtin_amdgcn_s_setprio(0);

#pragma unroll
        for (int msub = 0; msub < 2; msub++) {
            const int prow = msub * 16 + l15;
#pragma unroll
            for (int ksub = 0; ksub < 4; ksub++) {
                const float p0 = fexp2(fmaf(sc[msub][ksub][0], C1, -M2[msub]));
                const float p1 = fexp2(fmaf(sc[msub][ksub][1], C1, -M2[msub]));
                const float p2 = fexp2(fmaf(sc[msub][ksub][2], C1, -M2[msub]));
                const float p3 = fexp2(fmaf(sc[msub][ksub][3], C1, -M2[msub]));
                *(u16x4*)&PsL[w][swz(prow, ksub * 2 + (quad >> 1)) + (quad & 1) * 4] =
                    pack4(p0, p1, p2, p3);
            }
        }

        __builtin_amdgcn_s_setprio(1);
#pragma unroll
        for (int kj = 0; kj < 2; kj++) {
            f16x8 pa[2];
#pragma unroll
            for (int msub = 0; msub < 2; msub++)
                pa[msub] = *(const f16x8*)&PsL[w][swz(msub * 16 + l15, kj * 4 + quad)];
            lones[0] = __builtin_amdgcn_mfma_f32_16x16x32_f16(pa[0], ones, lones[0], 0, 0, 0);
            lones[1] = __builtin_amdgcn_mfma_f32_16x16x32_f16(pa[1], ones, lones[1], 0, 0, 0);
#pragma unroll
            for (int esub = 0; esub < 4; esub++) {
                f16x8 vr = *(const f16x8*)&VtL[cur][swz(esub * 16 + l15, kj * 4 + quad)];
                o[0][esub] = __builtin_amdgcn_mfma_f32_16x16x32_f16(pa[0], vr, o[0][esub], 0, 0, 0);
                o[1][esub] = __builtin_amdgcn_mfma_f32_16x16x32_f16(pa[1], vr, o[1][esub], 0, 0, 0);
            }
        }
        __builtin_amdgcn_s_setprio(0);

        if (t < NT - 2)       wait4_barrier();
        else if (t == NT - 2) wait0_barrier();
        cur = (cur == 2) ? 0 : cur + 1;
        pre = (pre == 2) ? 0 : pre + 1;
    }

    const int b = bh >> 4;
    const int h = bh & 15;
#pragma unroll
    for (int msub = 0; msub < 2; msub++) {
#pragma unroll
        for (int rr = 0; rr < 4; rr++) {
            const float linv = 1.0f / lones[msub][rr];
            const int row = q0 + w * 32 + msub * 16 + quad * 4 + rr;
#pragma unroll
            for (int esub = 0; esub < 4; esub++) {
                ctxh[((size_t)b * SS + row) * DD + h * HD + esub * 16 + l15] =
                    hbits((_Float16)(o[msub][esub][rr] * linv));
            }
        }
    }
}

// ---------------------------------------------------------------------------
extern "C" void kernel_launch(void* const* d_in, const int* in_sizes, int n_in,
                              void* d_out, int out_size, void* d_ws, size_t ws_size,
                              hipStream_t stream) {
    const float* X  = (const float*)d_in[0];
    const float* Wq = (const float*)d_in[1];
    const float* bq = (const float*)d_in[2];
    const float* Wk = (const float*)d_in[3];
    const float* bk = (const float*)d_in[4];
    const float* Wv = (const float*)d_in[5];
    const float* bv = (const float*)d_in[6];
    const float* Wo = (const float*)d_in[7];
    const float* bo = (const float*)d_in[8];
    float* out = (float*)d_out;

    // ws: Xh | WT(4096 rows) | qh | kh(swz) | vTs(swz) | ctxh | kc2
    const size_t NB2 = (size_t)4096 * 1024 * 2;   // 8388608 B
    unsigned char* w8 = (unsigned char*)d_ws;
    unsigned short* Xh   = (unsigned short*)(w8);
    unsigned short* WT   = (unsigned short*)(w8 + NB2);
    unsigned short* qh   = (unsigned short*)(w8 + 2 * NB2);
    unsigned short* kh   = (unsigned short*)(w8 + 3 * NB2);
    unsigned short* vTs  = (unsigned short*)(w8 + 4 * NB2);
    unsigned short* ctxh = (unsigned short*)(w8 + 5 * NB2);
    unsigned int*   kc2  = (unsigned int*)(w8 + 6 * NB2);
    unsigned short* WoT  = WT + (size_t)3072 * 1024;

    (void)hipMemsetAsync(kc2, 0, BB * HH * sizeof(unsigned int), stream);

    // 0) convert X + transpose/convert weights to fp16
    prep_convert<<<dim3(3072), 256, 0, stream>>>(X, Wq, Wk, Wv, Wo, Xh, WT);

    // 1) fused QKV projection: barrier-free wave-private staging,
    //    one head per block, Q/K/V fused over N (A-frag reuse x3).
    //    grid 16 heads x 32 m-tiles = 512 blocks = 2/CU exact.
    qkv_gemm<<<dim3(HH, 4096 / 128), 256, 0, stream>>>(
        Xh, WT, bq, bk, bv, qh, kh, vTs, kc2);

    // 2) MFMA flash attention (XCD swizzle, setprio, 3-buf counted-vmcnt)
    attn_mfma<<<dim3(SS / TQB, BB * HH), 256, 0, stream>>>(qh, kh, vTs, kc2, ctxh);

    // 3) output projection (128x64 tiles, 512 blocks = 2/CU, 3-buf,
    //    XCD swizzle)
    out_gemm<<<dim3(1024 / 64, 4096 / 128), 256, 0, stream>>>(ctxh, WoT, bo, out);
}

// Round 7
// 214.356 us; speedup vs baseline: 1.1299x; 1.1299x over previous
//
#include <hip/hip_runtime.h>
#include <hip/hip_bf16.h>
#include <math.h>

// Problem constants
#define BB 2
#define SS 2048
#define DD 1024
#define HH 16
#define HD 64

typedef __attribute__((ext_vector_type(8))) _Float16 f16x8;
typedef __attribute__((ext_vector_type(2))) __fp16 fp16x2;
typedef __attribute__((ext_vector_type(8))) unsigned short u16x8;
typedef __attribute__((ext_vector_type(4))) float f32x4;
typedef __attribute__((ext_vector_type(16))) float f32x16;
typedef __attribute__((ext_vector_type(4))) unsigned short u16x4;

__device__ __forceinline__ unsigned short hbits(_Float16 h) {
    union { _Float16 h; unsigned short s; } u; u.h = h; return u.s;
}

// XOR-swizzled 64x64 fp16 tile: off(row, col) = row*64 + ((col>>3 ^ row&7)<<3) + col&7
__device__ __forceinline__ int swz(int row, int grp) {
    return (row << 6) + (((grp) ^ (row & 7)) << 3);
}

__device__ __forceinline__ float fexp2(float x) {
#if __has_builtin(__builtin_amdgcn_exp2f)
    return __builtin_amdgcn_exp2f(x);
#else
    return exp2f(x);
#endif
}

__device__ __forceinline__ u16x4 pack4(float p0, float p1, float p2, float p3) {
#if __has_builtin(__builtin_amdgcn_cvt_pkrtz)
    union { fp16x2 h[2]; u16x4 u; } pu;
    pu.h[0] = __builtin_amdgcn_cvt_pkrtz(p0, p1);
    pu.h[1] = __builtin_amdgcn_cvt_pkrtz(p2, p3);
    return pu.u;
#else
    u16x4 r;
    r[0] = hbits((_Float16)p0); r[1] = hbits((_Float16)p1);
    r[2] = hbits((_Float16)p2); r[3] = hbits((_Float16)p3);
    return r;
#endif
}

// async global->LDS 16B/lane: lds dest = wave-uniform base + lane*16.
__device__ __forceinline__ void gload_lds16(const unsigned short* g, unsigned short* l) {
#if __has_builtin(__builtin_amdgcn_global_load_lds)
    auto gp = (const __attribute__((address_space(1))) unsigned int*)(uintptr_t)g;
    auto lp = (__attribute__((address_space(3))) unsigned int*)(uintptr_t)l;
    __builtin_amdgcn_global_load_lds(gp, lp, 16, 0, 0);
#else
    *(u16x8*)(l + (threadIdx.x & 63) * 8) = *(const u16x8*)g;
#endif
}

// Counted-vmcnt barriers: single asm blob so no load can slip between the
// wait and the barrier. Steady-state never drains vmcnt to 0 (T4).
__device__ __forceinline__ void wait4_barrier() {
    asm volatile("s_waitcnt vmcnt(4) lgkmcnt(0)\n\ts_barrier" ::: "memory");
}
__device__ __forceinline__ void wait6_barrier() {
    asm volatile("s_waitcnt vmcnt(6) lgkmcnt(0)\n\ts_barrier" ::: "memory");
}
__device__ __forceinline__ void wait0_barrier() {
    asm volatile("s_waitcnt vmcnt(0) lgkmcnt(0)\n\ts_barrier" ::: "memory");
}

// ---------------------------------------------------------------------------
// Prepass.
//  X  -> Xh2: fragment-major tiled fp16 for 32x32x16 MFMA A-frags:
//    frag(mblk32, kblk16) = 512 shorts in lane order:
//    Xh2[(mblk*64 + kblk)*512 + l*8 + j] = X[mblk*32 + (l&31)][kblk*16 + (l>>5)*8 + j]
//  Wq/Wk/Wv -> WT2: same tiled form over (n, k), nblk in [0,96).
//  Wo -> WoT: OLD row-major WT layout (out_gemm unchanged).
// ---------------------------------------------------------------------------
__global__ __launch_bounds__(256) void prep_convert(
    const float* __restrict__ X,
    const float* __restrict__ Wq, const float* __restrict__ Wk,
    const float* __restrict__ Wv, const float* __restrict__ Wo,
    unsigned short* __restrict__ Xh2, unsigned short* __restrict__ WT)
{
    __shared__ __align__(16) unsigned short LT[64 * 68];
    const int bid = blockIdx.x;
    const int tid = threadIdx.x;

    if (bid < 2048) {
        // X part: block = (mblk = bid>>4, kgroup = bid&15 covering 4 kblk16)
        const int mblk = bid >> 4;
        const int kg   = bid & 15;
        // coalesced read of the 32x64 fp32 region -> LDS [32][68] fp16
        {
            const int r  = tid >> 3;
            const int c0 = (tid & 7) * 8;
            const float* src = X + (size_t)(mblk * 32 + r) * DD + kg * 64 + c0;
            float4 a = *(const float4*)src;
            float4 b = *(const float4*)(src + 4);
            unsigned short* d = &LT[r * 68 + c0];
            d[0] = hbits((_Float16)a.x); d[1] = hbits((_Float16)a.y);
            d[2] = hbits((_Float16)a.z); d[3] = hbits((_Float16)a.w);
            d[4] = hbits((_Float16)b.x); d[5] = hbits((_Float16)b.y);
            d[6] = hbits((_Float16)b.z); d[7] = hbits((_Float16)b.w);
        }
        __syncthreads();
        // frag writeout: thread = (fb_local = tid>>6, lane = tid&63)
        const int fbl = tid >> 6, l = tid & 63;
        const int row = l & 31, c = fbl * 16 + (l >> 5) * 8;
        u16x8 v = *(const u16x8*)&LT[row * 68 + c];
        *(u16x8*)&Xh2[((size_t)mblk * 64 + kg * 4 + fbl) * 512 + l * 8] = v;
        return;
    }

    const int t = bid - 2048;
    if (t < 768) {
        // Q/K/V weights -> tiled WT2
        const int nt = t >> 4, ktile = t & 15;
        const int sel = nt >> 4, hh = nt & 15;
        const float* Ws = (sel == 0) ? Wq : ((sel == 1) ? Wk : Wv);
        const float* src = Ws + (size_t)hh * (DD * HD) + (size_t)ktile * 64 * HD;
        const int outRow0 = nt * 64;     // n offset (multiple of 64)
        const int kcol0   = ktile * 64;  // k offset (multiple of 64)

        const int e = tid & 63, dq = tid >> 6;
#pragma unroll
        for (int p = 0; p < 16; p++) {
            const int dl = p * 4 + dq;
            LT[e * 68 + dl] = hbits((_Float16)src[(size_t)dl * HD + e]);
        }
        __syncthreads();
        // 8 frag blocks: fb -> (nb = fb>>2, kb = fb&3)
#pragma unroll
        for (int p = 0; p < 2; p++) {
            const int sidx = p * 2048 + tid * 8;
            const int fb = sidx >> 9;
            const int l  = (sidx >> 3) & 63;
            const int nb = fb >> 2, kb = fb & 3;
            const int ee = nb * 32 + (l & 31);
            const int dl = kb * 16 + (l >> 5) * 8;
            u16x8 v = *(const u16x8*)&LT[ee * 68 + dl];
            *(u16x8*)&WT[(((size_t)(outRow0 >> 5) + nb) * 64 + (kcol0 >> 4) + kb) * 512
                         + l * 8] = v;
        }
    } else {
        // Wo -> OLD row-major WoT (rows 3072..4095), unchanged from before
        const int tt = t - 768;
        const int nt = tt & 15, ktile = tt >> 4;
        const float* src = Wo + (size_t)ktile * 64 * DD + nt * 64;
        const int outRow0 = 3072 + nt * 64;
        const int kcol0 = ktile * 64;

        const int e = tid & 63, dq = tid >> 6;
#pragma unroll
        for (int p = 0; p < 16; p++) {
            const int dl = p * 4 + dq;
            LT[e * 68 + dl] = hbits((_Float16)src[(size_t)dl * DD + e]);
        }
        __syncthreads();
        const int eo = tid >> 2, d16 = (tid & 3) * 16;
#pragma unroll
        for (int j = 0; j < 4; j++) {
            *(ushort4*)&WT[(size_t)(outRow0 + eo) * DD + kcol0 + d16 + j * 4] =
                *(const ushort4*)&LT[eo * 68 + d16 + j * 4];
        }
    }
}

// ---------------------------------------------------------------------------
// QKV GEMM with 32x32x16 MFMA: 128x128 tile, BK=32, 4 waves (2x2), wave =
// 64x64 out via 2x2 f32x16 accs -> 8 MFMA + 8 ds_read_b128 per iter (HALF
// the MFMA instruction count of the 16x16 version, same operand bytes).
// 3-buf depth-2 counted-vmcnt (r5 skeleton), 48 KiB LDS, 3 blocks/CU.
// Frag-major LDS chunks fed by tiled Xh2/WT2 -> conflict-free lane*16B reads.
// ---------------------------------------------------------------------------
#define GBM 128
#define GBN 128
#define GBK 64
#define NKT (DD / GBK)   // 16 (out_gemm)
#define QBK 32
#define QNKT (DD / QBK)  // 32 (qkv_gemm)

__global__ __launch_bounds__(256, 3) void qkv_gemm(
    const unsigned short* __restrict__ Xh2, const unsigned short* __restrict__ WT2,
    const float* __restrict__ bq, const float* __restrict__ bk,
    const float* __restrict__ bv,
    unsigned short* __restrict__ qh, unsigned short* __restrict__ kh,
    unsigned short* __restrict__ vTs, unsigned int* __restrict__ kc2)
{
    // per buffer: A = 8 frags (rb 0..3 x kb 0..1), B = 8 frags; 1 KB each.
    __shared__ __align__(16) unsigned short As[3][8 * 512];
    __shared__ __align__(16) unsigned short Bs[3][8 * 512];

    const int tid  = threadIdx.x;
    const int m0   = blockIdx.y * GBM;
    const int n0   = blockIdx.x * GBN;
    const int lane = tid & 63;
    const int w    = tid >> 6;
    const int wm   = w & 1, wn = w >> 1;
    const int l31  = lane & 31, h = lane >> 5;

    f32x16 acc[2][2];
#pragma unroll
    for (int i = 0; i < 2; i++)
#pragma unroll
        for (int j = 0; j < 2; j++)
#pragma unroll
            for (int k = 0; k < 16; k++) acc[i][j][k] = 0.f;

    const size_t mb0 = (size_t)(m0 >> 5);   // A mblk base (4 blks per tile)
    const size_t nb0 = (size_t)(n0 >> 5);   // B nblk base

    // stage K-tile t into buffer buf: 16 frags, 4 per wave (c = p*4 + w)
    auto STAGE = [&](int buf, int t) {
#pragma unroll
        for (int p = 0; p < 4; p++) {
            const int c = p * 4 + w;                   // 0..15
            const unsigned short* src;
            unsigned short* dst;
            if (c < 8) {
                src = Xh2 + ((mb0 + (c >> 1)) * 64 + t * 2 + (c & 1)) * 512 + lane * 8;
                dst = &As[buf][c * 512];
            } else {
                const int d = c - 8;
                src = WT2 + ((nb0 + (d >> 1)) * 64 + t * 2 + (d & 1)) * 512 + lane * 8;
                dst = &Bs[buf][d * 512];
            }
            gload_lds16(src, dst);
        }
    };

    STAGE(0, 0);
    STAGE(1, 1);
    wait0_barrier();

    int cur = 0, pre = 2;
    for (int t = 0; t < QNKT; t++) {
        if (t + 2 < QNKT) STAGE(pre, t + 2);
        f16x8 af[2][2], bf[2][2];
#pragma unroll
        for (int mi = 0; mi < 2; mi++)
#pragma unroll
            for (int kb = 0; kb < 2; kb++)
                af[mi][kb] = *(const f16x8*)
                    &As[cur][(((wm * 2 + mi) << 1) + kb) * 512 + lane * 8];
#pragma unroll
        for (int ni = 0; ni < 2; ni++)
#pragma unroll
            for (int kb = 0; kb < 2; kb++)
                bf[ni][kb] = *(const f16x8*)
                    &Bs[cur][(((wn * 2 + ni) << 1) + kb) * 512 + lane * 8];
#pragma unroll
        for (int kb = 0; kb < 2; kb++)
#pragma unroll
            for (int mi = 0; mi < 2; mi++)
#pragma unroll
                for (int ni = 0; ni < 2; ni++)
                    acc[mi][ni] = __builtin_amdgcn_mfma_f32_32x32x16_f16(
                        af[mi][kb], bf[ni][kb], acc[mi][ni], 0, 0, 0);
        if (t < QNKT - 2)       wait4_barrier();
        else if (t == QNKT - 2) wait0_barrier();
        cur = (cur == 2) ? 0 : cur + 1;
        pre = (pre == 2) ? 0 : pre + 1;
    }

    // epilogue. 32x32 C/D mapping [m74/m101]: col = lane&31,
    // row = (reg&3) + 8*(reg>>2) + 4*(lane>>5).
    const int sel = n0 >> 10;
    const int hw  = ((n0 + wn * 64) >> 6) & 15;
    const int bblk = m0 >> 11;
    const float* bias = (sel == 0) ? bq : ((sel == 1) ? bk : bv);
    const size_t bh_base = ((size_t)bblk * HH + hw) * (size_t)SS * HD;
    float wmx = 0.0f;
#pragma unroll
    for (int mi = 0; mi < 2; mi++) {
#pragma unroll
        for (int r = 0; r < 16; r++) {
            const int srow = wm * 64 + mi * 32 + (r & 3) + 8 * (r >> 2) + 4 * h;
            const int s = (m0 + srow) & (SS - 1);
            const int s63 = s & 63;
            float v2 = 0.0f;
#pragma unroll
            for (int ni = 0; ni < 2; ni++) {
                const int e = ni * 32 + l31;
                const float val = acc[mi][ni][r] + bias[hw * HD + e];
                if (sel == 0) {
                    qh[bh_base + (size_t)s * HD + e] = hbits((_Float16)val);
                } else if (sel == 1) {
                    v2 = fmaf(val, val, v2);
                    kh[bh_base + (size_t)(s >> 6) * 4096 + swz(s63, e >> 3) + (e & 7)] =
                        hbits((_Float16)val);
                } else {
                    vTs[bh_base + (size_t)(s >> 6) * 4096 + swz(e, s63 >> 3) + (s63 & 7)] =
                        hbits((_Float16)val);
                }
            }
            if (sel == 1) {
                // row-sum across the 32 cols held by this half-wave
                v2 += __shfl_xor(v2, 1);
                v2 += __shfl_xor(v2, 2);
                v2 += __shfl_xor(v2, 4);
                v2 += __shfl_xor(v2, 8);
                v2 += __shfl_xor(v2, 16);
                wmx = fmaxf(wmx, v2);
            }
        }
    }
    if (sel == 1) {
        wmx = fmaxf(wmx, __shfl_xor(wmx, 32));
        if (lane == 0)
            atomicMax(&kc2[bblk * HH + hw], __float_as_uint(wmx));
    }
}

// ---------------------------------------------------------------------------
// out GEMM 128x64: grid 512 = 2 blocks/CU exact, 3-buf depth-2 counted
// vmcnt, XCD swizzle (512 = 8 x 64). Unchanged from round 5.
// ---------------------------------------------------------------------------
__global__ __launch_bounds__(256, 2) void out_gemm(
    const unsigned short* __restrict__ Ctxh, const unsigned short* __restrict__ WoT,
    const float* __restrict__ bo, float* __restrict__ out)
{
    __shared__ __align__(16) unsigned short As[3][16 * 512];
    __shared__ __align__(16) unsigned short Bs[3][8 * 512];

    const int tid = threadIdx.x;
    const int f  = blockIdx.y * 16 + blockIdx.x;
    const int fs = (f & 7) * 64 + (f >> 3);
    const int bx = fs % 16, by = fs / 16;
    const int m0 = by * 128;
    const int n0 = bx * 64;
    const int lane = tid & 63;
    const int w = tid >> 6;
    const int wm = w & 1, wn = w >> 1;
    const int l15 = lane & 15, quad = lane >> 4;

    int g_off[4];
#pragma unroll
    for (int p = 0; p < 4; p++) {
        const int c = p * 4 + w;
        g_off[p] = ((c >> 1) * 16 + l15) * DD + (c & 1) * 32 + quad * 8;
    }

    f32x4 acc[4][2];
#pragma unroll
    for (int i = 0; i < 4; i++)
#pragma unroll
        for (int j = 0; j < 2; j++) acc[i][j] = (f32x4){0.f, 0.f, 0.f, 0.f};

    const unsigned short* Abase = Ctxh + (size_t)m0 * DD;
    const unsigned short* Bbase = WoT + (size_t)n0 * DD;

#pragma unroll
    for (int p = 0; p < 4; p++)
        gload_lds16(Abase + g_off[p], &As[0][(p * 4 + w) * 512]);
#pragma unroll
    for (int p = 0; p < 2; p++)
        gload_lds16(Bbase + g_off[p], &Bs[0][(p * 4 + w) * 512]);
#pragma unroll
    for (int p = 0; p < 4; p++)
        gload_lds16(Abase + g_off[p] + GBK, &As[1][(p * 4 + w) * 512]);
#pragma unroll
    for (int p = 0; p < 2; p++)
        gload_lds16(Bbase + g_off[p] + GBK, &Bs[1][(p * 4 + w) * 512]);
    wait0_barrier();

    int cur = 0, pre = 2;
    for (int it = 0; it < NKT; it++) {
        if (it + 2 < NKT) {
            const int kt2 = (it + 2) * GBK;
#pragma unroll
            for (int p = 0; p < 4; p++)
                gload_lds16(Abase + g_off[p] + kt2, &As[pre][(p * 4 + w) * 512]);
#pragma unroll
            for (int p = 0; p < 2; p++)
                gload_lds16(Bbase + g_off[p] + kt2, &Bs[pre][(p * 4 + w) * 512]);
        }
#pragma unroll
        for (int ks = 0; ks < 2; ks++) {
            f16x8 af[4], bf[2];
#pragma unroll
            for (int i = 0; i < 4; i++)
                af[i] = *(const f16x8*)&As[cur][((wm * 4 + i) * 2 + ks) * 512 + lane * 8];
#pragma unroll
            for (int j = 0; j < 2; j++)
                bf[j] = *(const f16x8*)&Bs[cur][((wn * 2 + j) * 2 + ks) * 512 + lane * 8];
#pragma unroll
            for (int ns = 0; ns < 2; ns++)
#pragma unroll
                for (int ms = 0; ms < 4; ms++)
                    acc[ms][ns] = __builtin_amdgcn_mfma_f32_16x16x32_f16(
                        af[ms], bf[ns], acc[ms][ns], 0, 0, 0);
        }
        if (it < NKT - 2)       wait6_barrier();
        else if (it == NKT - 2) wait0_barrier();
        cur = (cur == 2) ? 0 : cur + 1;
        pre = (pre == 2) ? 0 : pre + 1;
    }

#pragma unroll
    for (int ms = 0; ms < 4; ms++) {
#pragma unroll
        for (int rr = 0; rr < 4; rr++) {
            const size_t m = (size_t)(m0 + wm * 64 + ms * 16 + quad * 4 + rr);
#pragma unroll
            for (int ns = 0; ns < 2; ns++) {
                const int n = n0 + wn * 32 + ns * 16 + l15;
                out[m * DD + n] = acc[ms][ns][rr] + bo[n];
            }
        }
    }
}

// ---------------------------------------------------------------------------
// fp16 MFMA flash attention (S^T), fixed-m softmax, triple-buffered counted-
// vmcnt DMA, XCD swizzle, setprio. Unchanged from round 5.
// ---------------------------------------------------------------------------
#define TQB 128
#define TKB 64
#define NT (SS / TKB)    // 32
#define C1 0.1803368801111204f   // 0.125 * log2(e)

__global__ __launch_bounds__(256, 2) void attn_mfma(
    const unsigned short* __restrict__ qh, const unsigned short* __restrict__ kh,
    const unsigned short* __restrict__ vTs, const unsigned int* __restrict__ kc2,
    unsigned short* __restrict__ ctxh)
{
    __shared__ __align__(16) unsigned short KL [3][TKB * 64];
    __shared__ __align__(16) unsigned short VtL[3][HD * 64];
    __shared__ __align__(16) unsigned short PsL[4][32 * 64];

    const int tid  = threadIdx.x;
    const int lane = tid & 63;
    const int w    = tid >> 6;
    const int l15  = lane & 15;
    const int quad = lane >> 4;
    const int f  = blockIdx.y * 16 + blockIdx.x;
    const int fs = (f & 7) * 64 + (f >> 3);
    const int bh = fs >> 4;
    const int q0 = (fs & 15) * TQB;

    const float kfac = sqrtf(__uint_as_float(kc2[bh])) * 1.01f * C1;

    f16x8 qf[2][2];
    float M2[2];
#pragma unroll
    for (int msub = 0; msub < 2; msub++) {
        const unsigned short* qrow =
            qh + ((size_t)bh * SS + q0 + w * 32 + msub * 16 + l15) * HD;
        float nq2 = 0.0f;
#pragma unroll
        for (int dstep = 0; dstep < 2; dstep++) {
            qf[msub][dstep] = *(const f16x8*)&qrow[dstep * 32 + quad * 8];
#pragma unroll
            for (int j = 0; j < 8; j++) {
                const float x = (float)qf[msub][dstep][j];
                nq2 = fmaf(x, x, nq2);
            }
        }
        nq2 += __shfl_xor(nq2, 16);
        nq2 += __shfl_xor(nq2, 32);
        M2[msub] = sqrtf(nq2) * kfac;
    }

    f16x8 ones;
#pragma unroll
    for (int j = 0; j < 8; j++) ones[j] = (_Float16)1.0f;

    f32x4 o[2][4], lones[2];
#pragma unroll
    for (int ms = 0; ms < 2; ms++) {
        lones[ms] = (f32x4){0.f, 0.f, 0.f, 0.f};
#pragma unroll
        for (int e = 0; e < 4; e++) o[ms][e] = (f32x4){0.f, 0.f, 0.f, 0.f};
    }

    const unsigned short* kb0 = kh  + (size_t)bh * SS * HD;
    const unsigned short* vb0 = vTs + (size_t)bh * SS * HD;

    gload_lds16(kb0 + tid * 8,        &KL [0][w * 512]);
    gload_lds16(kb0 + 2048 + tid * 8, &KL [0][2048 + w * 512]);
    gload_lds16(vb0 + tid * 8,        &VtL[0][w * 512]);
    gload_lds16(vb0 + 2048 + tid * 8, &VtL[0][2048 + w * 512]);
    gload_lds16(kb0 + 4096 + tid * 8, &KL [1][w * 512]);
    gload_lds16(kb0 + 6144 + tid * 8, &KL [1][2048 + w * 512]);
    gload_lds16(vb0 + 4096 + tid * 8, &VtL[1][w * 512]);
    gload_lds16(vb0 + 6144 + tid * 8, &VtL[1][2048 + w * 512]);
    wait0_barrier();

    int cur = 0, pre = 2;
    for (int t = 0; t < NT; t++) {
        if (t + 2 < NT) {
            const unsigned short* kb = kb0 + (size_t)(t + 2) * 4096;
            const unsigned short* vb = vb0 + (size_t)(t + 2) * 4096;
            gload_lds16(kb + tid * 8,        &KL [pre][w * 512]);
            gload_lds16(kb + 2048 + tid * 8, &KL [pre][2048 + w * 512]);
            gload_lds16(vb + tid * 8,        &VtL[pre][w * 512]);
            gload_lds16(vb + 2048 + tid * 8, &VtL[pre][2048 + w * 512]);
        }

        f32x4 sc[2][4];
        __builtin_amdgcn_s_setprio(1);
#pragma unroll
        for (int ksub = 0; ksub < 4; ksub++) {
            const int row = ksub * 16 + l15;
            f16x8 k0 = *(const f16x8*)&KL[cur][swz(row, quad)];
            f16x8 k1 = *(const f16x8*)&KL[cur][swz(row, 4 + quad)];
#pragma unroll
            for (int msub = 0; msub < 2; msub++) {
                f32x4 a = (f32x4){0.f, 0.f, 0.f, 0.f};
                a = __builtin_amdgcn_mfma_f32_16x16x32_f16(k0, qf[msub][0], a, 0, 0, 0);
                a = __builtin_amdgcn_mfma_f32_16x16x32_f16(k1, qf[msub][1], a, 0, 0, 0);
                sc[msub][ksub] = a;
            }
        }
        __builtin_amdgcn_s_setprio(0);

#pragma unroll
        for (int msub = 0; msub < 2; msub++) {
            const int prow = msub * 16 + l15;
#pragma unroll
            for (int ksub = 0; ksub < 4; ksub++) {
                const float p0 = fexp2(fmaf(sc[msub][ksub][0], C1, -M2[msub]));
                const float p1 = fexp2(fmaf(sc[msub][ksub][1], C1, -M2[msub]));
                const float p2 = fexp2(fmaf(sc[msub][ksub][2], C1, -M2[msub]));
                const float p3 = fexp2(fmaf(sc[msub][ksub][3], C1, -M2[msub]));
                *(u16x4*)&PsL[w][swz(prow, ksub * 2 + (quad >> 1)) + (quad & 1) * 4] =
                    pack4(p0, p1, p2, p3);
            }
        }

        __builtin_amdgcn_s_setprio(1);
#pragma unroll
        for (int kj = 0; kj < 2; kj++) {
            f16x8 pa[2];
#pragma unroll
            for (int msub = 0; msub < 2; msub++)
                pa[msub] = *(const f16x8*)&PsL[w][swz(msub * 16 + l15, kj * 4 + quad)];
            lones[0] = __builtin_amdgcn_mfma_f32_16x16x32_f16(pa[0], ones, lones[0], 0, 0, 0);
            lones[1] = __builtin_amdgcn_mfma_f32_16x16x32_f16(pa[1], ones, lones[1], 0, 0, 0);
#pragma unroll
            for (int esub = 0; esub < 4; esub++) {
                f16x8 vr = *(const f16x8*)&VtL[cur][swz(esub * 16 + l15, kj * 4 + quad)];
                o[0][esub] = __builtin_amdgcn_mfma_f32_16x16x32_f16(pa[0], vr, o[0][esub], 0, 0, 0);
                o[1][esub] = __builtin_amdgcn_mfma_f32_16x16x32_f16(pa[1], vr, o[1][esub], 0, 0, 0);
            }
        }
        __builtin_amdgcn_s_setprio(0);

        if (t < NT - 2)       wait4_barrier();
        else if (t == NT - 2) wait0_barrier();
        cur = (cur == 2) ? 0 : cur + 1;
        pre = (pre == 2) ? 0 : pre + 1;
    }

    const int b = bh >> 4;
    const int hh = bh & 15;
#pragma unroll
    for (int msub = 0; msub < 2; msub++) {
#pragma unroll
        for (int rr = 0; rr < 4; rr++) {
            const float linv = 1.0f / lones[msub][rr];
            const int row = q0 + w * 32 + msub * 16 + quad * 4 + rr;
#pragma unroll
            for (int esub = 0; esub < 4; esub++) {
                ctxh[((size_t)b * SS + row) * DD + hh * HD + esub * 16 + l15] =
                    hbits((_Float16)(o[msub][esub][rr] * linv));
            }
        }
    }
}

// ---------------------------------------------------------------------------
extern "C" void kernel_launch(void* const* d_in, const int* in_sizes, int n_in,
                              void* d_out, int out_size, void* d_ws, size_t ws_size,
                              hipStream_t stream) {
    const float* X  = (const float*)d_in[0];
    const float* Wq = (const float*)d_in[1];
    const float* bq = (const float*)d_in[2];
    const float* Wk = (const float*)d_in[3];
    const float* bk = (const float*)d_in[4];
    const float* Wv = (const float*)d_in[5];
    const float* bv = (const float*)d_in[6];
    const float* Wo = (const float*)d_in[7];
    const float* bo = (const float*)d_in[8];
    float* out = (float*)d_out;

    // ws: Xh2(tiled) | WT(WT2 tiled + WoT old) | qh | kh(swz) | vTs(swz) | ctxh | kc2
    const size_t NB2 = (size_t)4096 * 1024 * 2;   // 8388608 B
    unsigned char* w8 = (unsigned char*)d_ws;
    unsigned short* Xh2  = (unsigned short*)(w8);
    unsigned short* WT   = (unsigned short*)(w8 + NB2);
    unsigned short* qh   = (unsigned short*)(w8 + 2 * NB2);
    unsigned short* kh   = (unsigned short*)(w8 + 3 * NB2);
    unsigned short* vTs  = (unsigned short*)(w8 + 4 * NB2);
    unsigned short* ctxh = (unsigned short*)(w8 + 5 * NB2);
    unsigned int*   kc2  = (unsigned int*)(w8 + 6 * NB2);
    unsigned short* WoT  = WT + (size_t)3072 * 1024;

    (void)hipMemsetAsync(kc2, 0, BB * HH * sizeof(unsigned int), stream);

    // 0) convert X -> tiled Xh2, Wq/Wk/Wv -> tiled WT2, Wo -> old WoT
    prep_convert<<<dim3(3072), 256, 0, stream>>>(X, Wq, Wk, Wv, Wo, Xh2, WT);

    // 1) fused QKV projection (32x32x16 MFMA, BK=32, 3-buf counted-vmcnt,
    //    3 blocks/CU)
    qkv_gemm<<<dim3(3072 / GBN, 4096 / GBM), 256, 0, stream>>>(
        Xh2, WT, bq, bk, bv, qh, kh, vTs, kc2);

    // 2) MFMA flash attention (XCD swizzle, setprio, 3-buf counted-vmcnt)
    attn_mfma<<<dim3(SS / TQB, BB * HH), 256, 0, stream>>>(qh, kh, vTs, kc2, ctxh);

    // 3) output projection (128x64 tiles, 512 blocks = 2/CU, 3-buf,
    //    XCD swizzle)
    out_gemm<<<dim3(1024 / 64, 4096 / 128), 256, 0, stream>>>(ctxh, WoT, bo, out);
}